// Round 1
// 214.668 us; speedup vs baseline: 1.0084x; 1.0084x over previous
//
#include <hip/hip_runtime.h>

#define BATCH 32768
#define SEQ 512
#define TPL 8          // timesteps per lane (64 lanes * 8 = 512)
#define EPS 1e-8f

// One wave per row, lane i owns t in [8i, 8i+8).
// ret_t = a_t*ret_{t+1} + b_t;  a_t = g*lam_t, b_t = r_t + g*(1-lam_t)*v_{t+1},
// g = gamma*(1-d_t). Per-lane affine summary -> 6-step wave suffix scan ->
// per-lane replay.
//
// v3: ZERO LDS, ZERO barriers. All 15 global loads per lane are independent
// and issued up front (single vmcnt latency exposure per wave) instead of the
// old two-phase stage->syncthreads->load structure whose barrier forced a
// full vmcnt(0) drain between two HBM round trips.
//   - values[row][1+8i .. 1+8i+8): per-lane scalar dwords (stride 32B across
//     lanes). All 8 insts hit the same ~17 cache lines per row; j=0 misses,
//     j>0 hit L1 -> same HBM traffic as the old dense staging, no LDS trip.
//   - lam: lane's own aligned float4 pair of raw_lambd + 8 tanhf in-lane
//     (lambda was never shared across lanes; the block-wide stage was waste).
__global__ void __launch_bounds__(256)
glr_wave_scan3(const float* __restrict__ values,
               const float* __restrict__ rewards,
               const float* __restrict__ dones,
               const float* __restrict__ raw_gamma,
               const float* __restrict__ raw_lambd,
               float* __restrict__ out) {
    const int lane = threadIdx.x & 63;
    const int wv   = threadIdx.x >> 6;
    const int row  = blockIdx.x * 4 + wv;
    const int t0   = lane * TPL;

    const float* __restrict__ vrow = values  + (size_t)row * (SEQ + 1);
    const float* __restrict__ rrow = rewards + (size_t)row * SEQ + t0;
    const float* __restrict__ drow = dones   + (size_t)row * SEQ + t0;
    float*       __restrict__ orow = out     + (size_t)row * SEQ + t0;

    // ---- issue ALL independent global loads up front (max MLP, no barrier) ----
    float vj[TPL];
    #pragma unroll
    for (int j = 0; j < TPL; ++j)
        vj[j] = vrow[1 + t0 + j];            // misaligned run -> scalar dwords

    const float4 r4a = *(const float4*)(rrow);
    const float4 r4b = *(const float4*)(rrow + 4);
    const float4 d4a = *(const float4*)(drow);
    const float4 d4b = *(const float4*)(drow + 4);
    const float4 l4a = *(const float4*)(raw_lambd + t0);      // 32B-aligned
    const float4 l4b = *(const float4*)(raw_lambd + t0 + 4);
    const float vlast = vrow[SEQ];           // wave-uniform address (1 line)

    const float gamma = fmaxf(tanhf(raw_gamma[0]), EPS);

    float rj[TPL] = {r4a.x, r4a.y, r4a.z, r4a.w, r4b.x, r4b.y, r4b.z, r4b.w};
    float dj[TPL] = {d4a.x, d4a.y, d4a.z, d4a.w, d4b.x, d4b.y, d4b.z, d4b.w};
    const float lr[TPL] = {l4a.x, l4a.y, l4a.z, l4a.w, l4b.x, l4b.y, l4b.z, l4b.w};
    float lm[TPL];
    #pragma unroll
    for (int j = 0; j < TPL; ++j)
        lm[j] = fmaxf(tanhf(lr[j]), EPS);    // in-lane; +~6% VALU, no LDS/barrier

    // ---- per-lane affine summary (t descending) ----
    float a[TPL], b[TPL];
    float A = 1.f, Bv = 0.f;
    #pragma unroll
    for (int j = TPL - 1; j >= 0; --j) {
        const float g = gamma * (1.f - dj[j]);
        a[j] = g * lm[j];
        b[j] = fmaf(g * (1.f - lm[j]), vj[j], rj[j]);
        Bv = fmaf(a[j], Bv, b[j]);
        A  = a[j] * A;
    }

    // ---- wave-level inclusive suffix scan of (A,B) ----
    #pragma unroll
    for (int dlt = 1; dlt < 64; dlt <<= 1) {
        const float oA = __shfl_down(A, dlt, 64);
        const float oB = __shfl_down(Bv, dlt, 64);
        if (lane + dlt < 64) {                // compose(mine, downstream)
            Bv = fmaf(A, oB, Bv);
            A  = A * oA;
        }
    }
    // exclusive: lane i needs suffix starting at lane i+1
    float EA = __shfl_down(A, 1, 64);
    float EB = __shfl_down(Bv, 1, 64);
    if (lane == 63) { EA = 1.f; EB = 0.f; }

    // ret at this lane's right boundary; values[row][SEQ] is the scan init
    float ret = fmaf(EA, vlast, EB);

    // ---- replay, emit outputs ----
    float o[TPL];
    #pragma unroll
    for (int j = TPL - 1; j >= 0; --j) {
        ret = fmaf(a[j], ret, b[j]);
        o[j] = ret;
    }
    *(float4*)(orow)     = make_float4(o[0], o[1], o[2], o[3]);
    *(float4*)(orow + 4) = make_float4(o[4], o[5], o[6], o[7]);
}

extern "C" void kernel_launch(void* const* d_in, const int* in_sizes, int n_in,
                              void* d_out, int out_size, void* d_ws, size_t ws_size,
                              hipStream_t stream) {
    const float* values    = (const float*)d_in[0];
    const float* rewards   = (const float*)d_in[1];
    const float* dones     = (const float*)d_in[2];
    const float* raw_gamma = (const float*)d_in[3];
    const float* raw_lambd = (const float*)d_in[4];
    float* out = (float*)d_out;

    const int block = 256;                 // 4 waves = 4 rows per block
    const int grid = BATCH / 4;            // 8192 blocks
    glr_wave_scan3<<<grid, block, 0, stream>>>(
        values, rewards, dones, raw_gamma, raw_lambd, out);
}